// Round 2
// baseline (134.442 us; speedup 1.0000x reference)
//
#include <hip/hip_runtime.h>
#include <math.h>

#define HH 496
#define WW 496
#define HWSZ (HH*WW)
#define NW 31
#define NWIN (NW*NW)   // 961

__constant__ float c_thetas[8] = {
    0.39269908169872414f, 0.7853981633974483f, 1.1780972450961724f,
    1.5707963267948966f,  1.9634954084936207f, 2.356194490192345f,
    2.748893571891069f,   3.141592653589793f};

// ---- Kernel 1: build the 72x5x5 Gabor bank + zero the 9 mean accumulators ----
__global__ void bank_kernel(const float* __restrict__ sigmas,
                            const float* __restrict__ lambdas,
                            float* __restrict__ filt,
                            float* __restrict__ meanacc) {
    int idx = threadIdx.x + blockIdx.x * blockDim.x;
    if (idx >= 1800) {
        if (idx < 1809) meanacc[(idx - 1800) * 16] = 0.0f;  // one per 64B line
        return;
    }
    int f = idx / 25, k = idx % 25;
    int dy = k / 5, dx = k % 5;
    int s = f / 24, rem = f % 24, l = rem / 8, t = rem % 8;
    float sig = sigmas[s], lam = lambdas[l], th = c_thetas[t];
    float y = (float)dy - 2.0f, x = (float)dx - 2.0f;
    float st = sinf(th), ct = cosf(th);
    float yt = -x * st + y * ct;
    float xt =  x * ct + y * st;
    float sx2 = sig * sig;          // sigma_x = sig
    float sy2 = 4.0f * sig * sig;   // sigma_y = sig/0.5
    float g = expf(-0.5f * (xt * xt / sx2 + yt * yt / sy2)) *
              cosf(6.28318530717958647692f * xt / lam + 1.5707963267948966f);
    filt[idx] = g;
}

// ---- Kernel 2: conv + max over 8 thetas -> out[9][496][496], atomic channel sums ----
__global__ __launch_bounds__(256) void conv_kernel(
    const float* __restrict__ img, const float* __restrict__ filt,
    float* __restrict__ out, float* __restrict__ meanacc) {
    __shared__ float tile[20 * 20];
    __shared__ float red[4][9];
    int tid = threadIdx.x;
    int tx = tid & 15, ty = tid >> 4;
    int bx = blockIdx.x, by = blockIdx.y;

    for (int i = tid; i < 400; i += 256) {
        int tY = i / 20, tX = i % 20;
        int gy = by * 16 + tY - 2, gx = bx * 16 + tX - 2;
        float v = 0.0f;
        if (gy >= 0 && gy < HH && gx >= 0 && gx < WW) v = img[gy * WW + gx];
        tile[i] = v;
    }
    __syncthreads();

    float r[25];
#pragma unroll
    for (int dy = 0; dy < 5; dy++)
#pragma unroll
        for (int dx = 0; dx < 5; dx++)
            r[dy * 5 + dx] = tile[(ty + dy) * 20 + (tx + dx)];

    int y = by * 16 + ty, x = bx * 16 + tx;

    float sums[9];
#pragma unroll
    for (int c = 0; c < 9; c++) {
        float maxv = -3.402823466e38f;
#pragma unroll
        for (int t = 0; t < 8; t++) {
            const float* fp = filt + (c * 8 + t) * 25;  // wave-uniform -> s_load
            float acc = 0.0f;
#pragma unroll
            for (int k = 0; k < 25; k++) acc += r[k] * fp[k];
            maxv = fmaxf(maxv, acc);
        }
        out[c * HWSZ + y * WW + x] = maxv;
        sums[c] = maxv;
    }

    // single end-of-kernel reduction: wave butterfly -> LDS -> 9 atomics
#pragma unroll
    for (int c = 0; c < 9; c++) {
        float s = sums[c];
#pragma unroll
        for (int off = 32; off > 0; off >>= 1) s += __shfl_down(s, off, 64);
        if ((tid & 63) == 0) red[tid >> 6][c] = s;
    }
    __syncthreads();
    if (tid < 9)
        atomicAdd(&meanacc[tid * 16],
                  red[0][tid] + red[1][tid] + red[2][tid] + red[3][tid]);
}

// ---- Kernel 3: per-window keypoint test + patch extraction ----
__global__ __launch_bounds__(256) void patch_kernel(
    const float* __restrict__ out, const float* __restrict__ meanacc,
    float* __restrict__ dst) {
    int w = blockIdx.x;
    int r = w / NW, cl = w % NW;
    int tid = threadIdx.x;
    int wy = tid >> 4, wx = tid & 15;
    __shared__ int lds_and[4];
    __shared__ int lds_or[4];

    // Stage 1: valid = OR_c of AND_threads(center beats me per argmax tie rules)
    int okmask = 0;
#pragma unroll
    for (int c = 0; c < 9; c++) {
        float m5 = meanacc[c * 16] * (5.0f / (float)HWSZ);
        float v  = out[c * HWSZ + (r * 16 + wy) * WW + (cl * 16 + wx)];
        float vc = out[c * HWSZ + (r * 16 + 8) * WW + (cl * 16 + 0)]; // flat idx 128 = (8,0)
        float thr  = (v  > m5) ? v  : 0.0f;
        float thrc = (vc > m5) ? vc : 0.0f;
        // first-occurrence argmax: earlier strictly less, later (incl. center) <=
        bool ok = (tid < 128) ? (thr < thrc) : (thr <= thrc);
        okmask |= (ok ? 1 : 0) << c;
    }
#pragma unroll
    for (int off = 1; off < 64; off <<= 1) okmask &= __shfl_xor(okmask, off, 64);
    if ((tid & 63) == 0) lds_and[tid >> 6] = okmask;

    // Stage 2: load all 9 patches into registers, build nonzero bitmask
    float vals[9][4];
    int nzmask = 0;
#pragma unroll
    for (int c = 0; c < 9; c++) {
#pragma unroll
        for (int q = 0; q < 4; q++) {
            int e = q * 256 + tid;
            int i = e >> 5, j = e & 31;
            int row = r * 16 + i - 8;   // padded coord minus 16
            int col = cl * 16 + j - 8;
            float v = 0.0f;
            if (row >= 0 && row < HH && col >= 0 && col < WW)
                v = out[c * HWSZ + row * WW + col];
            vals[c][q] = v;
            if (v != 0.0f) nzmask |= 1 << c;
        }
    }
#pragma unroll
    for (int off = 1; off < 64; off <<= 1) nzmask |= __shfl_xor(nzmask, off, 64);
    if ((tid & 63) == 0) lds_or[tid >> 6] = nzmask;
    __syncthreads();

    int am = lds_and[0] & lds_and[1] & lds_and[2] & lds_and[3];
    int om = lds_or[0] | lds_or[1] | lds_or[2] | lds_or[3];
    bool valid = (am != 0);

#pragma unroll
    for (int c = 0; c < 9; c++) {
        float mk = (valid && ((om >> c) & 1)) ? 1.0f : 0.0f;
#pragma unroll
        for (int q = 0; q < 4; q++) {
            int e = q * 256 + tid;
            dst[(size_t)c * NWIN * 1024 + (size_t)w * 1024 + e] = vals[c][q] * mk;
        }
    }
}

extern "C" void kernel_launch(void* const* d_in, const int* in_sizes, int n_in,
                              void* d_out, int out_size, void* d_ws, size_t ws_size,
                              hipStream_t stream) {
    const float* img     = (const float*)d_in[0];
    const float* sigmas  = (const float*)d_in[1];
    const float* lambdas = (const float*)d_in[2];
    float* ws = (float*)d_ws;
    // ws layout (floats): filt[1800] @0, meanacc[9*16] @2048, out @4096
    float* filt    = ws;
    float* meanacc = ws + 2048;
    float* outb    = ws + 4096;   // 9*496*496 = 2,214,144 floats

    bank_kernel<<<8, 256, 0, stream>>>(sigmas, lambdas, filt, meanacc);
    conv_kernel<<<dim3(NW, NW), 256, 0, stream>>>(img, filt, outb, meanacc);
    patch_kernel<<<NWIN, 256, 0, stream>>>(outb, meanacc, (float*)d_out);
}

// Round 3
// 130.111 us; speedup vs baseline: 1.0333x; 1.0333x over previous
//
#include <hip/hip_runtime.h>
#include <math.h>

#define HH 496
#define WW 496
#define HWSZ (HH*WW)
#define NW 31
#define NWIN (NW*NW)   // 961

__constant__ float c_thetas[8] = {
    0.39269908169872414f, 0.7853981633974483f, 1.1780972450961724f,
    1.5707963267948966f,  1.9634954084936207f, 2.356194490192345f,
    2.748893571891069f,   3.141592653589793f};

// ---- Kernel 1: build the Gabor bank TRANSPOSED as filt[k][f] (k=0..24, f=0..71)
//      f = c*8 + t, c = s*3 + l. Also zero the 9 mean accumulators. ----
__global__ void bank_kernel(const float* __restrict__ sigmas,
                            const float* __restrict__ lambdas,
                            float* __restrict__ filt,
                            float* __restrict__ meanacc) {
    int idx = threadIdx.x + blockIdx.x * blockDim.x;
    if (idx >= 1800) {
        if (idx < 1809) meanacc[(idx - 1800) * 16] = 0.0f;  // one per 64B line
        return;
    }
    int f = idx / 25, k = idx % 25;
    int dy = k / 5, dx = k % 5;
    int s = f / 24, rem = f % 24, l = rem / 8, t = rem % 8;
    float sig = sigmas[s], lam = lambdas[l], th = c_thetas[t];
    float y = (float)dy - 2.0f, x = (float)dx - 2.0f;
    float st = sinf(th), ct = cosf(th);
    float yt = -x * st + y * ct;
    float xt =  x * ct + y * st;
    float sx2 = sig * sig;          // sigma_x = sig
    float sy2 = 4.0f * sig * sig;   // sigma_y = sig/0.5
    float g = expf(-0.5f * (xt * xt / sx2 + yt * yt / sy2)) *
              cosf(6.28318530717958647692f * xt / lam + 1.5707963267948966f);
    filt[k * 72 + f] = g;           // transposed layout
}

// ---- Kernel 2: conv + max over 8 thetas -> out[9][496][496] ----
// k-outer / f-inner: 72 accumulators live in VGPRs, 25 ds_reads total,
// filter values arrive via wave-uniform s_load (contiguous per k).
__global__ __launch_bounds__(256) void conv_kernel(
    const float* __restrict__ img, const float* __restrict__ filt,
    float* __restrict__ out, float* __restrict__ meanacc) {
    __shared__ float tile[20 * 20];
    __shared__ float red[4][9];
    int tid = threadIdx.x;
    int tx = tid & 15, ty = tid >> 4;
    int bx = blockIdx.x, by = blockIdx.y;

    for (int i = tid; i < 400; i += 256) {
        int tY = i / 20, tX = i % 20;
        int gy = by * 16 + tY - 2, gx = bx * 16 + tX - 2;
        float v = 0.0f;
        if (gy >= 0 && gy < HH && gx >= 0 && gx < WW) v = img[gy * WW + gx];
        tile[i] = v;
    }
    __syncthreads();

    float acc[72];
#pragma unroll
    for (int f = 0; f < 72; f++) acc[f] = 0.0f;

#pragma unroll
    for (int k = 0; k < 25; k++) {
        int dy = k / 5, dx = k % 5;
        float pix = tile[(ty + dy) * 20 + (tx + dx)];
        const float* fp = filt + k * 72;   // wave-uniform -> s_load_dwordx*
#pragma unroll
        for (int f = 0; f < 72; f++) acc[f] = fmaf(pix, fp[f], acc[f]);
    }

    int y = by * 16 + ty, x = bx * 16 + tx;

    float sums[9];
#pragma unroll
    for (int c = 0; c < 9; c++) {
        float maxv = acc[c * 8];
#pragma unroll
        for (int t = 1; t < 8; t++) maxv = fmaxf(maxv, acc[c * 8 + t]);
        out[c * HWSZ + y * WW + x] = maxv;
        sums[c] = maxv;
    }

    // single end-of-kernel reduction: wave butterfly -> LDS -> 9 atomics
#pragma unroll
    for (int c = 0; c < 9; c++) {
        float s = sums[c];
#pragma unroll
        for (int off = 32; off > 0; off >>= 1) s += __shfl_down(s, off, 64);
        if ((tid & 63) == 0) red[tid >> 6][c] = s;
    }
    __syncthreads();
    if (tid < 9)
        atomicAdd(&meanacc[tid * 16],
                  red[0][tid] + red[1][tid] + red[2][tid] + red[3][tid]);
}

// ---- Kernel 3: per-window keypoint test + patch extraction ----
__global__ __launch_bounds__(256) void patch_kernel(
    const float* __restrict__ out, const float* __restrict__ meanacc,
    float* __restrict__ dst) {
    int w = blockIdx.x;
    int r = w / NW, cl = w % NW;
    int tid = threadIdx.x;
    int wy = tid >> 4, wx = tid & 15;
    __shared__ int lds_and[4];
    __shared__ int lds_or[4];

    // Stage 1: valid = OR_c of AND_threads(center beats me per argmax tie rules)
    int okmask = 0;
#pragma unroll
    for (int c = 0; c < 9; c++) {
        float m5 = meanacc[c * 16] * (5.0f / (float)HWSZ);
        float v  = out[c * HWSZ + (r * 16 + wy) * WW + (cl * 16 + wx)];
        float vc = out[c * HWSZ + (r * 16 + 8) * WW + (cl * 16 + 0)]; // flat idx 128 = (8,0)
        float thr  = (v  > m5) ? v  : 0.0f;
        float thrc = (vc > m5) ? vc : 0.0f;
        // first-occurrence argmax: earlier strictly less, later (incl. center) <=
        bool ok = (tid < 128) ? (thr < thrc) : (thr <= thrc);
        okmask |= (ok ? 1 : 0) << c;
    }
#pragma unroll
    for (int off = 1; off < 64; off <<= 1) okmask &= __shfl_xor(okmask, off, 64);
    if ((tid & 63) == 0) lds_and[tid >> 6] = okmask;

    // Stage 2: load all 9 patches into registers, build nonzero bitmask
    float vals[9][4];
    int nzmask = 0;
#pragma unroll
    for (int c = 0; c < 9; c++) {
#pragma unroll
        for (int q = 0; q < 4; q++) {
            int e = q * 256 + tid;
            int i = e >> 5, j = e & 31;
            int row = r * 16 + i - 8;   // padded coord minus 16
            int col = cl * 16 + j - 8;
            float v = 0.0f;
            if (row >= 0 && row < HH && col >= 0 && col < WW)
                v = out[c * HWSZ + row * WW + col];
            vals[c][q] = v;
            if (v != 0.0f) nzmask |= 1 << c;
        }
    }
#pragma unroll
    for (int off = 1; off < 64; off <<= 1) nzmask |= __shfl_xor(nzmask, off, 64);
    if ((tid & 63) == 0) lds_or[tid >> 6] = nzmask;
    __syncthreads();

    int am = lds_and[0] & lds_and[1] & lds_and[2] & lds_and[3];
    int om = lds_or[0] | lds_or[1] | lds_or[2] | lds_or[3];
    bool valid = (am != 0);

#pragma unroll
    for (int c = 0; c < 9; c++) {
        float mk = (valid && ((om >> c) & 1)) ? 1.0f : 0.0f;
#pragma unroll
        for (int q = 0; q < 4; q++) {
            int e = q * 256 + tid;
            dst[(size_t)c * NWIN * 1024 + (size_t)w * 1024 + e] = vals[c][q] * mk;
        }
    }
}

extern "C" void kernel_launch(void* const* d_in, const int* in_sizes, int n_in,
                              void* d_out, int out_size, void* d_ws, size_t ws_size,
                              hipStream_t stream) {
    const float* img     = (const float*)d_in[0];
    const float* sigmas  = (const float*)d_in[1];
    const float* lambdas = (const float*)d_in[2];
    float* ws = (float*)d_ws;
    // ws layout (floats): filt[1800] @0, meanacc[9*16] @2048, out @4096
    float* filt    = ws;
    float* meanacc = ws + 2048;
    float* outb    = ws + 4096;   // 9*496*496 = 2,214,144 floats

    bank_kernel<<<8, 256, 0, stream>>>(sigmas, lambdas, filt, meanacc);
    conv_kernel<<<dim3(NW, NW), 256, 0, stream>>>(img, filt, outb, meanacc);
    patch_kernel<<<NWIN, 256, 0, stream>>>(outb, meanacc, (float*)d_out);
}

// Round 4
// 125.642 us; speedup vs baseline: 1.0700x; 1.0356x over previous
//
#include <hip/hip_runtime.h>
#include <math.h>

#define HH 496
#define WW 496
#define HWSZ (HH*WW)
#define NW 31
#define NWIN (NW*NW)   // 961

__constant__ float c_thetas[8] = {
    0.39269908169872414f, 0.7853981633974483f, 1.1780972450961724f,
    1.5707963267948966f,  1.9634954084936207f, 2.356194490192345f,
    2.748893571891069f,   3.141592653589793f};

// ---- Kernel 1: Gabor bank TRANSPOSED as filt[k][f] (k=0..24, f=c*8+t) + zero meanacc ----
__global__ void bank_kernel(const float* __restrict__ sigmas,
                            const float* __restrict__ lambdas,
                            float* __restrict__ filt,
                            float* __restrict__ meanacc) {
    int idx = threadIdx.x + blockIdx.x * blockDim.x;
    if (idx >= 1800) {
        if (idx < 1809) meanacc[(idx - 1800) * 16] = 0.0f;  // one per 64B line
        return;
    }
    int f = idx / 25, k = idx % 25;
    int dy = k / 5, dx = k % 5;
    int s = f / 24, rem = f % 24, l = rem / 8, t = rem % 8;
    float sig = sigmas[s], lam = lambdas[l], th = c_thetas[t];
    float y = (float)dy - 2.0f, x = (float)dx - 2.0f;
    float st = sinf(th), ct = cosf(th);
    float yt = -x * st + y * ct;
    float xt =  x * ct + y * st;
    float sx2 = sig * sig;          // sigma_x = sig
    float sy2 = 4.0f * sig * sig;   // sigma_y = sig/0.5
    float g = expf(-0.5f * (xt * xt / sx2 + yt * yt / sy2)) *
              cosf(6.28318530717958647692f * xt / lam + 1.5707963267948966f);
    filt[k * 72 + f] = g;           // transposed layout
}

// ---- Kernel 2: conv, channel-split: block z does channels [3z, 3z+3) = 24 filters ----
__global__ __launch_bounds__(256) void conv_kernel(
    const float* __restrict__ img, const float* __restrict__ filt,
    float* __restrict__ out, float* __restrict__ meanacc) {
    __shared__ float tile[20 * 20];
    __shared__ float red[4][3];
    int tid = threadIdx.x;
    int tx = tid & 15, ty = tid >> 4;
    int bx = blockIdx.x, by = blockIdx.y, cg = blockIdx.z;  // channel group

    for (int i = tid; i < 400; i += 256) {
        int tY = i / 20, tX = i % 20;
        int gy = by * 16 + tY - 2, gx = bx * 16 + tX - 2;
        float v = 0.0f;
        if (gy >= 0 && gy < HH && gx >= 0 && gx < WW) v = img[gy * WW + gx];
        tile[i] = v;
    }
    __syncthreads();

    float acc[24];
#pragma unroll
    for (int f = 0; f < 24; f++) acc[f] = 0.0f;

#pragma unroll
    for (int k = 0; k < 25; k++) {
        int dy = k / 5, dx = k % 5;
        float pix = tile[(ty + dy) * 20 + (tx + dx)];
        const float* fp = filt + k * 72 + cg * 24;  // wave-uniform -> s_load
#pragma unroll
        for (int f = 0; f < 24; f++) acc[f] = fmaf(pix, fp[f], acc[f]);
    }

    int y = by * 16 + ty, x = bx * 16 + tx;

    float sums[3];
#pragma unroll
    for (int cc = 0; cc < 3; cc++) {
        float maxv = acc[cc * 8];
#pragma unroll
        for (int t = 1; t < 8; t++) maxv = fmaxf(maxv, acc[cc * 8 + t]);
        out[(cg * 3 + cc) * HWSZ + y * WW + x] = maxv;
        sums[cc] = maxv;
    }

#pragma unroll
    for (int cc = 0; cc < 3; cc++) {
        float s = sums[cc];
#pragma unroll
        for (int off = 32; off > 0; off >>= 1) s += __shfl_down(s, off, 64);
        if ((tid & 63) == 0) red[tid >> 6][cc] = s;
    }
    __syncthreads();
    if (tid < 3)
        atomicAdd(&meanacc[(cg * 3 + tid) * 16],
                  red[0][tid] + red[1][tid] + red[2][tid] + red[3][tid]);
}

// ---- Kernel 3: per-window keypoint test -> valid[961] ----
__global__ __launch_bounds__(256) void valid_kernel(
    const float* __restrict__ out, const float* __restrict__ meanacc,
    int* __restrict__ valid) {
    int w = blockIdx.x;
    int r = w / NW, cl = w % NW;
    int tid = threadIdx.x;
    int wy = tid >> 4, wx = tid & 15;
    __shared__ int lds_and[4];

    int okmask = 0;
#pragma unroll
    for (int c = 0; c < 9; c++) {
        float m5 = meanacc[c * 16] * (5.0f / (float)HWSZ);
        float v  = out[c * HWSZ + (r * 16 + wy) * WW + (cl * 16 + wx)];
        float vc = out[c * HWSZ + (r * 16 + 8) * WW + (cl * 16 + 0)]; // flat idx 128 = (8,0)
        float thr  = (v  > m5) ? v  : 0.0f;
        float thrc = (vc > m5) ? vc : 0.0f;
        // first-occurrence argmax: earlier strictly less, later (incl. center) <=
        bool ok = (tid < 128) ? (thr < thrc) : (thr <= thrc);
        okmask |= (ok ? 1 : 0) << c;
    }
#pragma unroll
    for (int off = 1; off < 64; off <<= 1) okmask &= __shfl_xor(okmask, off, 64);
    if ((tid & 63) == 0) lds_and[tid >> 6] = okmask;
    __syncthreads();
    if (tid == 0)
        valid[w] = (lds_and[0] & lds_and[1] & lds_and[2] & lds_and[3]) != 0 ? 1 : 0;
}

// ---- Kernel 4: patch copy, one block per (window, channel), float4 per thread ----
__global__ __launch_bounds__(256) void patch_copy_kernel(
    const float* __restrict__ out, const int* __restrict__ valid,
    float* __restrict__ dst) {
    int w = blockIdx.x, c = blockIdx.y;
    int r = w / NW, cl = w % NW;
    int tid = threadIdx.x;
    int i = tid >> 3;            // patch row 0..31
    int jg = (tid & 7) << 2;     // patch col group 0,4,...,28

    int row = r * 16 + i - 8;
    int col = cl * 16 + jg - 8;
    float4 v = make_float4(0.f, 0.f, 0.f, 0.f);
    // 4-aligned col groups never straddle the [0,496) edge (496 % 4 == 0)
    if (row >= 0 && row < HH && col >= 0) {
        if (col + 3 < WW)
            v = *(const float4*)(out + (size_t)c * HWSZ + (size_t)row * WW + col);
    }
    bool nzl = (v.x != 0.f) || (v.y != 0.f) || (v.z != 0.f) || (v.w != 0.f);
    int nz = __syncthreads_or(nzl ? 1 : 0);
    float mk = (valid[w] && nz) ? 1.0f : 0.0f;
    v.x *= mk; v.y *= mk; v.z *= mk; v.w *= mk;
    *(float4*)(dst + (size_t)c * NWIN * 1024 + (size_t)w * 1024 + i * 32 + jg) = v;
}

extern "C" void kernel_launch(void* const* d_in, const int* in_sizes, int n_in,
                              void* d_out, int out_size, void* d_ws, size_t ws_size,
                              hipStream_t stream) {
    const float* img     = (const float*)d_in[0];
    const float* sigmas  = (const float*)d_in[1];
    const float* lambdas = (const float*)d_in[2];
    float* ws = (float*)d_ws;
    // ws layout (floats): filt[1800] @0, meanacc[144] @2048, valid[961] @2240, out @4096
    float* filt    = ws;
    float* meanacc = ws + 2048;
    int*   valid   = (int*)(ws + 2240);
    float* outb    = ws + 4096;   // 9*496*496 = 2,214,144 floats

    bank_kernel<<<8, 256, 0, stream>>>(sigmas, lambdas, filt, meanacc);
    conv_kernel<<<dim3(NW, NW, 3), 256, 0, stream>>>(img, filt, outb, meanacc);
    valid_kernel<<<NWIN, 256, 0, stream>>>(outb, meanacc, valid);
    patch_copy_kernel<<<dim3(NWIN, 9), 256, 0, stream>>>(outb, valid, (float*)d_out);
}

// Round 5
// 122.183 us; speedup vs baseline: 1.1003x; 1.0283x over previous
//
#include <hip/hip_runtime.h>
#include <math.h>

#define HH 496
#define WW 496
#define HWSZ (HH*WW)
#define NW 31
#define NWIN (NW*NW)   // 961

__constant__ float c_thetas[8] = {
    0.39269908169872414f, 0.7853981633974483f, 1.1780972450961724f,
    1.5707963267948966f,  1.9634954084936207f, 2.356194490192345f,
    2.748893571891069f,   3.141592653589793f};

// ---- Kernel 1: Gabor bank TRANSPOSED as filt[k][f] (k=0..24, f=c*8+t) + zero meanacc ----
__global__ void bank_kernel(const float* __restrict__ sigmas,
                            const float* __restrict__ lambdas,
                            float* __restrict__ filt,
                            float* __restrict__ meanacc) {
    int idx = threadIdx.x + blockIdx.x * blockDim.x;
    if (idx >= 1800) {
        if (idx < 1809) meanacc[(idx - 1800) * 16] = 0.0f;  // one per 64B line
        return;
    }
    int f = idx / 25, k = idx % 25;
    int dy = k / 5, dx = k % 5;
    int s = f / 24, rem = f % 24, l = rem / 8, t = rem % 8;
    float sig = sigmas[s], lam = lambdas[l], th = c_thetas[t];
    float y = (float)dy - 2.0f, x = (float)dx - 2.0f;
    float st = sinf(th), ct = cosf(th);
    float yt = -x * st + y * ct;
    float xt =  x * ct + y * st;
    float sx2 = sig * sig;          // sigma_x = sig
    float sy2 = 4.0f * sig * sig;   // sigma_y = sig/0.5
    float g = expf(-0.5f * (xt * xt / sx2 + yt * yt / sy2)) *
              cosf(6.28318530717958647692f * xt / lam + 1.5707963267948966f);
    filt[k * 72 + f] = g;           // transposed layout
}

// ---- Kernel 2: conv, channel-split: block z does channels [3z, 3z+3) = 24 filters ----
__global__ __launch_bounds__(256) void conv_kernel(
    const float* __restrict__ img, const float* __restrict__ filt,
    float* __restrict__ out, float* __restrict__ meanacc) {
    __shared__ float tile[20 * 20];
    __shared__ float red[4][3];
    int tid = threadIdx.x;
    int tx = tid & 15, ty = tid >> 4;
    int bx = blockIdx.x, by = blockIdx.y, cg = blockIdx.z;  // channel group

    for (int i = tid; i < 400; i += 256) {
        int tY = i / 20, tX = i % 20;
        int gy = by * 16 + tY - 2, gx = bx * 16 + tX - 2;
        float v = 0.0f;
        if (gy >= 0 && gy < HH && gx >= 0 && gx < WW) v = img[gy * WW + gx];
        tile[i] = v;
    }
    __syncthreads();

    float acc[24];
#pragma unroll
    for (int f = 0; f < 24; f++) acc[f] = 0.0f;

#pragma unroll
    for (int k = 0; k < 25; k++) {
        int dy = k / 5, dx = k % 5;
        float pix = tile[(ty + dy) * 20 + (tx + dx)];
        const float* fp = filt + k * 72 + cg * 24;  // wave-uniform -> s_load
#pragma unroll
        for (int f = 0; f < 24; f++) acc[f] = fmaf(pix, fp[f], acc[f]);
    }

    int y = by * 16 + ty, x = bx * 16 + tx;

    float sums[3];
#pragma unroll
    for (int cc = 0; cc < 3; cc++) {
        float maxv = acc[cc * 8];
#pragma unroll
        for (int t = 1; t < 8; t++) maxv = fmaxf(maxv, acc[cc * 8 + t]);
        out[(cg * 3 + cc) * HWSZ + y * WW + x] = maxv;
        sums[cc] = maxv;
    }

#pragma unroll
    for (int cc = 0; cc < 3; cc++) {
        float s = sums[cc];
#pragma unroll
        for (int off = 32; off > 0; off >>= 1) s += __shfl_down(s, off, 64);
        if ((tid & 63) == 0) red[tid >> 6][cc] = s;
    }
    __syncthreads();
    if (tid < 3)
        atomicAdd(&meanacc[(cg * 3 + tid) * 16],
                  red[0][tid] + red[1][tid] + red[2][tid] + red[3][tid]);
}

// ---- Kernel 3: fused per-window validity + 9-channel patch copy, one barrier ----
__global__ __launch_bounds__(256) void patch_kernel(
    const float* __restrict__ out, const float* __restrict__ meanacc,
    float* __restrict__ dst) {
    int w = blockIdx.x;
    int r = w / NW, cl = w % NW;
    int tid = threadIdx.x;
    __shared__ int lds_and[4];
    __shared__ int lds_or[4];

    // Stage 1: per-channel "argmax of thresholded window == 128" bit, AND over threads
    int wy = tid >> 4, wx = tid & 15;
    int okmask = 0;
#pragma unroll
    for (int c = 0; c < 9; c++) {
        float m5 = meanacc[c * 16] * (5.0f / (float)HWSZ);
        float v  = out[c * HWSZ + (r * 16 + wy) * WW + (cl * 16 + wx)];
        float vc = out[c * HWSZ + (r * 16 + 8) * WW + (cl * 16 + 0)]; // flat idx 128 = (8,0)
        float thr  = (v  > m5) ? v  : 0.0f;
        float thrc = (vc > m5) ? vc : 0.0f;
        // first-occurrence argmax: earlier strictly less, later (incl. center) <=
        bool ok = (tid < 128) ? (thr < thrc) : (thr <= thrc);
        okmask |= (ok ? 1 : 0) << c;
    }
#pragma unroll
    for (int off = 1; off < 64; off <<= 1) okmask &= __shfl_xor(okmask, off, 64);
    if ((tid & 63) == 0) lds_and[tid >> 6] = okmask;

    // Stage 2: one float4 per (thread, channel); nonzero bitmask OR over threads
    int i = tid >> 3;            // patch row 0..31
    int jg = (tid & 7) << 2;     // patch col group 0,4,...,28
    int row = r * 16 + i - 8;
    int col = cl * 16 + jg - 8;
    // 4-aligned col groups never straddle the [0,496) edge (496 % 4 == 0)
    bool inb = (row >= 0 && row < HH && col >= 0 && col + 3 < WW);
    float4 vals[9];
    int nzmask = 0;
#pragma unroll
    for (int c = 0; c < 9; c++) {
        float4 v = make_float4(0.f, 0.f, 0.f, 0.f);
        if (inb)
            v = *(const float4*)(out + (size_t)c * HWSZ + (size_t)row * WW + col);
        vals[c] = v;
        if (v.x != 0.f || v.y != 0.f || v.z != 0.f || v.w != 0.f) nzmask |= 1 << c;
    }
#pragma unroll
    for (int off = 1; off < 64; off <<= 1) nzmask |= __shfl_xor(nzmask, off, 64);
    if ((tid & 63) == 0) lds_or[tid >> 6] = nzmask;
    __syncthreads();

    int am = lds_and[0] & lds_and[1] & lds_and[2] & lds_and[3];
    int om = lds_or[0] | lds_or[1] | lds_or[2] | lds_or[3];
    bool valid = (am != 0);

#pragma unroll
    for (int c = 0; c < 9; c++) {
        float mk = (valid && ((om >> c) & 1)) ? 1.0f : 0.0f;
        float4 v = vals[c];
        v.x *= mk; v.y *= mk; v.z *= mk; v.w *= mk;
        *(float4*)(dst + (size_t)c * NWIN * 1024 + (size_t)w * 1024 + i * 32 + jg) = v;
    }
}

extern "C" void kernel_launch(void* const* d_in, const int* in_sizes, int n_in,
                              void* d_out, int out_size, void* d_ws, size_t ws_size,
                              hipStream_t stream) {
    const float* img     = (const float*)d_in[0];
    const float* sigmas  = (const float*)d_in[1];
    const float* lambdas = (const float*)d_in[2];
    float* ws = (float*)d_ws;
    // ws layout (floats): filt[1800] @0, meanacc[144] @2048, out @4096
    float* filt    = ws;
    float* meanacc = ws + 2048;
    float* outb    = ws + 4096;   // 9*496*496 = 2,214,144 floats

    bank_kernel<<<8, 256, 0, stream>>>(sigmas, lambdas, filt, meanacc);
    conv_kernel<<<dim3(NW, NW, 3), 256, 0, stream>>>(img, filt, outb, meanacc);
    patch_kernel<<<NWIN, 256, 0, stream>>>(outb, meanacc, (float*)d_out);
}